// Round 5
// baseline (339.447 us; speedup 1.0000x reference)
//
#include <hip/hip_runtime.h>
#include <hip/hip_bf16.h>
#include <math.h>
#include <stdint.h>

#define B 2
#define H 16
#define L 2048
#define D 64
#define NB 32
#define PTS 72            // P tile row stride in u16 (144 B)

typedef unsigned short u16;
typedef unsigned int u32;
typedef __attribute__((ext_vector_type(2))) unsigned int u32x2;
typedef __attribute__((ext_vector_type(4))) unsigned short u16x4;
typedef __attribute__((ext_vector_type(8))) unsigned short u16x8;
typedef __attribute__((ext_vector_type(8))) short s16x8;
typedef __attribute__((ext_vector_type(4))) float f32x4;

union FragU { s16x8 v; u32 u[4]; };

__device__ __forceinline__ u32 pkbf(float a, float b) {
  __hip_bfloat162 h = __float22bfloat162_rn(make_float2(a, b));  // v_cvt_pk_bf16_f32
  union { __hip_bfloat162 h; u32 u; } cv; cv.h = h; return cv.u;
}
__device__ __forceinline__ float bf2f(u32 u16bits) {
  union { u32 u; float f; } c; c.u = u16bits << 16; return c.f;
}
// split float4 -> packed hi (u32x2) + lo (u32x2), RNE both levels
__device__ __forceinline__ void split4(float4 p, u32x2& hi, u32x2& lo) {
  u32 h01 = pkbf(p.x, p.y), h23 = pkbf(p.z, p.w);
  float rx = p.x - bf2f(h01 & 0xffffu);
  float ry = p.y - bf2f(h01 >> 16);
  float rz = p.z - bf2f(h23 & 0xffffu);
  float rw = p.w - bf2f(h23 >> 16);
  hi = (u32x2){h01, h23};
  lo = (u32x2){pkbf(rx, ry), pkbf(rz, rw)};
}

// ---------------------------------------------------------------------------
// k_prep: per (bh,j): K column-sums, K split hi/lo, V^T split hi/lo,
//         per-bh max ||k_row||^2
// ---------------------------------------------------------------------------
__global__ __launch_bounds__(256) void k_prep(const float* __restrict__ k,
                                              const float* __restrict__ v,
                                              float* __restrict__ ksum,
                                              u16* __restrict__ khi_g,
                                              u16* __restrict__ klo_g,
                                              u16* __restrict__ vthi_g,
                                              u16* __restrict__ vtlo_g,
                                              float* __restrict__ kmax2g) {
  int blk = blockIdx.x, bh = blk >> 5, j = blk & 31, t = threadIdx.x;
  __shared__ float vt[64 * 65];
  __shared__ float pk_[4][64];
  __shared__ unsigned bmaxS;
  if (t == 0) bmaxS = 0u;
  size_t base = (size_t)blk * 4096;
  {
    int d = t & 63, g = t >> 6;
    float sk = 0.f;
    for (int r = g * 16; r < g * 16 + 16; ++r) sk += k[base + r * 64 + d];
    pk_[g][d] = sk;
  }
  __syncthreads();
  if (t < 64) ksum[(size_t)blk * 64 + t] = pk_[0][t] + pk_[1][t] + pk_[2][t] + pk_[3][t];

  float rmax = 0.f;
  for (int it = 0; it < 4; ++it) {
    int idx = t + 256 * it, r = idx >> 4, c4 = (idx & 15) * 4;
    float4 f = *(const float4*)(k + base + r * 64 + c4);
    u32x2 hi, lo; split4(f, hi, lo);
    *(u32x2*)(khi_g + base + r * 64 + c4) = hi;
    *(u32x2*)(klo_g + base + r * 64 + c4) = lo;
    float ssq = f.x*f.x + f.y*f.y + f.z*f.z + f.w*f.w;
    ssq += __shfl_xor(ssq, 1); ssq += __shfl_xor(ssq, 2);
    ssq += __shfl_xor(ssq, 4); ssq += __shfl_xor(ssq, 8);
    if ((t & 15) == 0) rmax = fmaxf(rmax, ssq);
    float4 g2 = *(const float4*)(v + base + r * 64 + c4);
    vt[(c4 + 0) * 65 + r] = g2.x;
    vt[(c4 + 1) * 65 + r] = g2.y;
    vt[(c4 + 2) * 65 + r] = g2.z;
    vt[(c4 + 3) * 65 + r] = g2.w;
  }
  if ((t & 15) == 0) atomicMax(&bmaxS, __float_as_uint(rmax));
  __syncthreads();
  if (t == 0) atomicMax((unsigned*)(kmax2g + bh), bmaxS);
  for (int it = 0; it < 2; ++it) {
    int idx = t + 256 * it, d = idx >> 3, s8 = (idx & 7) * 8;
    const float* vr = &vt[d * 65 + s8];
    float4 f0 = {vr[0], vr[1], vr[2], vr[3]};
    float4 f1 = {vr[4], vr[5], vr[6], vr[7]};
    u32x2 h0, l0, h1, l1;
    split4(f0, h0, l0); split4(f1, h1, l1);
    size_t o = (size_t)bh * 131072 + (size_t)d * 2048 + j * 64 + s8;
    *(u32x2*)(vthi_g + o) = h0; *(u32x2*)(vthi_g + o + 4) = h1;
    *(u32x2*)(vtlo_g + o) = l0; *(u32x2*)(vtlo_g + o + 4) = l1;
  }
}

// ---------------------------------------------------------------------------
// k_attn: fused mask + two-pass MFMA attention (S^T = K·Q^T, O^T = V^T·P^T)
// XCD-swizzled grid: bh = blk & 31 -> all 32 WGs of a bh on one XCD (%8)
// ---------------------------------------------------------------------------
__global__ __launch_bounds__(256, 4) void k_attn(
    const float* __restrict__ q,
    const float* __restrict__ ksum,
    const u16* __restrict__ khi_g, const u16* __restrict__ klo_g,
    const u16* __restrict__ vthi_g, const u16* __restrict__ vtlo_g,
    const float* __restrict__ cdfthreshd, const float* __restrict__ simthreshd1,
    const float* __restrict__ pvthreshd, const float* __restrict__ kmax2g,
    float* __restrict__ out) {
  int blk = blockIdx.x, bh = blk & 31, i = blk >> 5, h = bh & (H - 1);
  int t = threadIdx.x, lane = t & 63, w = t >> 6;
  int m16 = lane & 15, quad = lane >> 4;

  __shared__ __align__(16) uint8_t smem[28688];
  float* qf32  = (float*)smem;                    // 64 x 68 f32, setup only (aliases pbuf)
  u32*   rbm   = (u32*)(smem + 18432);            // 64 x 33 uint keys (-(s-M))
  float* MS    = (float*)(smem + 26880);          // 64
  float* linvS = (float*)(smem + 27136);          // 64
  float* lpart = (float*)(smem + 27392);          // [4][64]
  float* qmS   = (float*)(smem + 28416);          // 64
  int*   pooledS = (int*)(smem + 28672);
  u32*   mwS     = (u32*)(smem + 28676);
  u32*   gmS     = (u32*)(smem + 28680);
  u16* ph_ = (u16*)smem;                          // P hi plane (pass B)
  u16* pl_ = (u16*)(smem + 9216);                 // P lo plane

  const float* qg = q + ((size_t)bh * L + (size_t)i * 64) * D;
  const u16* kh = khi_g + (size_t)bh * (L * D);
  const u16* kl = klo_g + (size_t)bh * (L * D);
  const u16* vh = vthi_g + (size_t)bh * (L * D);
  const u16* vl = vtlo_g + (size_t)bh * (L * D);

  // ---- Q B-fragments straight from global (f32 -> split, registers) ----
  s16x8 qhf[4][2], qlf[4][2];
#pragma unroll
  for (int nt = 0; nt < 4; ++nt)
#pragma unroll
    for (int ks = 0; ks < 2; ++ks) {
      const float* p0 = qg + (16 * nt + m16) * 64 + ks * 32 + quad * 8;
      float4 a = *(const float4*)p0;
      float4 b2 = *(const float4*)(p0 + 4);
      u32x2 ha, la, hb, lb;
      split4(a, ha, la); split4(b2, hb, lb);
      FragU fh, fl;
      fh.u[0] = ha[0]; fh.u[1] = ha[1]; fh.u[2] = hb[0]; fh.u[3] = hb[1];
      fl.u[0] = la[0]; fl.u[1] = la[1]; fl.u[2] = lb[0]; fl.u[3] = lb[1];
      qhf[nt][ks] = fh.v; qlf[nt][ks] = fl.v;
    }
  // stage Q f32 for mask math
  for (int it = 0; it < 4; ++it) {
    int idx = t + 256 * it, r = idx >> 4, c4 = (idx & 15) * 4;
    *(float4*)&qf32[r * 68 + c4] = ((const float4*)qg)[idx];
  }
  for (int e = t; e < 64 * 33; e += 256) rbm[e] = 0x7F800000u;  // +inf keys
  __syncthreads();

  // ---- wave0: qm (block mean of this q-block) ----
  if (w == 0) {
    float s = 0.f;
    for (int r = 0; r < 64; ++r) s += qf32[r * 68 + lane];
    qmS[lane] = s * (1.f / 64.f);
  }
  __syncthreads();

  // ---- wave0: CDF block-keep; wave1: pooled cosine + M rows ----
  bool keepj = false;
  if (w == 0 && lane < 32) {
    int j = lane;
    const float* ksp = ksum + (size_t)bh * NB * 64 + j * 64;
    float sv = 0.f;
    for (int d = 0; d < 64; ++d) sv += qmS[d] * ksp[d];
    sv *= (1.f / 64.f) * 0.125f;     // mean shift cancels in softmax
    float mx = sv;
    for (int off = 16; off; off >>= 1) mx = fmaxf(mx, __shfl_xor(mx, off, 32));
    float p = expf(sv - mx);
    float sum = p;
    for (int off = 16; off; off >>= 1) sum += __shfl_xor(sum, off, 32);
    p /= sum;
    float excl = 0.f;
    for (int u = 0; u < 32; ++u) {
      float pu = __shfl(p, u, 32);
      if ((pu > p) || (pu == p && u < j)) excl += pu;
    }
    keepj = excl < cdfthreshd[h];
  }
  if (w == 1) {
    int r = lane;
    float dot = 0.f, qn2 = 0.f, qmn2 = 0.f;
    for (int d = 0; d < 64; ++d) {
      float a = qf32[r * 68 + d], b2 = qmS[d];
      dot += a * b2; qn2 += a * a; qmn2 += b2 * b2;
    }
    float cs = dot / (sqrtf(qn2) * sqrtf(qmn2) + 1e-6f);
    float su = cs;
    for (int off = 32; off; off >>= 1) su += __shfl_xor(su, off);
    if (lane == 0) *pooledS = (su * (1.f / 64.f)) > simthreshd1[h];
    MS[r] = sqrtf(qn2 * kmax2g[bh]) * 0.125f;   // M_r = ||q_r||*Kmax*scale >= |s|
  }
  __syncthreads();
  if (w == 0 && lane < 32) {
    bool bit = keepj || !(*pooledS) || (lane == 0);
    unsigned long long bal = __ballot(bit);
    if (lane == 0) *mwS = (u32)bal;
  }
  __syncthreads();
  u32 mw = *mwS;

  float Mq[4];
#pragma unroll
  for (int nt = 0; nt < 4; ++nt) Mq[nt] = MS[16 * nt + m16];

  // ---- Pass A: barrier-free; K A-frags from global; per-lane l; rbm atomics ----
  float lp[4] = {0.f, 0.f, 0.f, 0.f};
  {
    int j = (int)__builtin_ctz(mw);
    u32 rm_ = mw & (mw - 1);
    s16x8 ka[2][2], kan[2][2];
    const u16* kr0 = kh + (size_t)(j * 64 + 16 * w + m16) * 64 + quad * 8;
    const u16* kl0 = kl + (size_t)(j * 64 + 16 * w + m16) * 64 + quad * 8;
#pragma unroll
    for (int ks = 0; ks < 2; ++ks) {
      ka[ks][0] = *(const s16x8*)(kr0 + ks * 32);
      ka[ks][1] = *(const s16x8*)(kl0 + ks * 32);
    }
    for (;;) {
      int nj = -1;
      if (rm_) {
        nj = (int)__builtin_ctz(rm_); rm_ &= rm_ - 1;
        const u16* nr = kh + (size_t)(nj * 64 + 16 * w + m16) * 64 + quad * 8;
        const u16* nl = kl + (size_t)(nj * 64 + 16 * w + m16) * 64 + quad * 8;
#pragma unroll
        for (int ks = 0; ks < 2; ++ks) {
          kan[ks][0] = *(const s16x8*)(nr + ks * 32);
          kan[ks][1] = *(const s16x8*)(nl + ks * 32);
        }
      }
      f32x4 acc[4];
#pragma unroll
      for (int nt = 0; nt < 4; ++nt) acc[nt] = (f32x4){0.f, 0.f, 0.f, 0.f};
#pragma unroll
      for (int ks = 0; ks < 2; ++ks)
#pragma unroll
        for (int nt = 0; nt < 4; ++nt) {
          acc[nt] = __builtin_amdgcn_mfma_f32_16x16x32_bf16(ka[ks][0], qhf[nt][ks], acc[nt], 0, 0, 0);
          acc[nt] = __builtin_amdgcn_mfma_f32_16x16x32_bf16(ka[ks][1], qhf[nt][ks], acc[nt], 0, 0, 0);
          acc[nt] = __builtin_amdgcn_mfma_f32_16x16x32_bf16(ka[ks][0], qlf[nt][ks], acc[nt], 0, 0, 0);
        }
#pragma unroll
      for (int nt = 0; nt < 4; ++nt) {
        float vmax = -1e30f;
#pragma unroll
        for (int reg = 0; reg < 4; ++reg) {
          float s = acc[nt][reg] * 0.125f - Mq[nt];
          lp[nt] += __expf(s);
          vmax = fmaxf(vmax, s);
        }
        vmax = fmaxf(vmax, __shfl_xor(vmax, 16));
        vmax = fmaxf(vmax, __shfl_xor(vmax, 32));
        if (quad == 0)
          atomicMin(&rbm[(16 * nt + m16) * 33 + j], __float_as_uint(fmaxf(-vmax, 0.f)));
      }
      if (nj < 0) break;
#pragma unroll
      for (int ks = 0; ks < 2; ++ks) { ka[ks][0] = kan[ks][0]; ka[ks][1] = kan[ks][1]; }
      j = nj;
    }
  }
#pragma unroll
  for (int nt = 0; nt < 4; ++nt) {
    float s = lp[nt];
    s += __shfl_xor(s, 16); s += __shfl_xor(s, 32);
    if (quad == 0) lpart[w * 64 + 16 * nt + m16] = s;
  }
  __syncthreads();
  if (t < 64) linvS[t] = 1.f / (lpart[t] + lpart[64 + t] + lpart[128 + t] + lpart[192 + t]);
  __syncthreads();

  // ---- PV gate ----
  if (t < 32) {
    bool keep = (mw >> t) & 1u;
    if (keep && t != 0) {
      float thr = pvthreshd[h] * 1e-3f;
      float mp = 0.f;
      for (int r = 0; r < 64; ++r) {
        float key = __uint_as_float(rbm[r * 33 + t]);
        mp = fmaxf(mp, __expf(-key) * linvS[r]);
      }
      keep = mp >= thr;
    }
    unsigned long long bal = __ballot(keep);
    if (t == 0) *gmS = (u32)bal;
  }
  __syncthreads();
  u32 gm = *gmS;

  // ---- Pass B: S recompute -> P^T (single LDS buf) -> O^T += V^T . P^T ----
  float linq[4];
#pragma unroll
  for (int nt = 0; nt < 4; ++nt) linq[nt] = linvS[16 * nt + m16];
  f32x4 oacc[4];
#pragma unroll
  for (int nt = 0; nt < 4; ++nt) oacc[nt] = (f32x4){0.f, 0.f, 0.f, 0.f};

  {
    int j = -1;
    u32 g2 = gm;
    s16x8 ka[2][2];
    if (g2) {
      j = (int)__builtin_ctz(g2); g2 &= g2 - 1;
      const u16* kr0 = kh + (size_t)(j * 64 + 16 * w + m16) * 64 + quad * 8;
      const u16* kl0 = kl + (size_t)(j * 64 + 16 * w + m16) * 64 + quad * 8;
#pragma unroll
      for (int ks = 0; ks < 2; ++ks) {
        ka[ks][0] = *(const s16x8*)(kr0 + ks * 32);
        ka[ks][1] = *(const s16x8*)(kl0 + ks * 32);
      }
    }
    while (j >= 0) {
      // V^T A-frags for current j
      s16x8 va[2][2];
      const u16* vr0 = vh + (size_t)(16 * w + m16) * L + j * 64 + quad * 8;
      const u16* vl0 = vl + (size_t)(16 * w + m16) * L + j * 64 + quad * 8;
#pragma unroll
      for (int ks = 0; ks < 2; ++ks) {
        va[ks][0] = *(const s16x8*)(vr0 + ks * 32);
        va[ks][1] = *(const s16x8*)(vl0 + ks * 32);
      }
      f32x4 acc[4];
#pragma unroll
      for (int nt = 0; nt < 4; ++nt) acc[nt] = (f32x4){0.f, 0.f, 0.f, 0.f};
#pragma unroll
      for (int ks = 0; ks < 2; ++ks)
#pragma unroll
        for (int nt = 0; nt < 4; ++nt) {
          acc[nt] = __builtin_amdgcn_mfma_f32_16x16x32_bf16(ka[ks][0], qhf[nt][ks], acc[nt], 0, 0, 0);
          acc[nt] = __builtin_amdgcn_mfma_f32_16x16x32_bf16(ka[ks][1], qhf[nt][ks], acc[nt], 0, 0, 0);
          acc[nt] = __builtin_amdgcn_mfma_f32_16x16x32_bf16(ka[ks][0], qlf[nt][ks], acc[nt], 0, 0, 0);
        }
      // prefetch next K
      int nj = -1;
      if (g2) {
        nj = (int)__builtin_ctz(g2); g2 &= g2 - 1;
        const u16* nr = kh + (size_t)(nj * 64 + 16 * w + m16) * 64 + quad * 8;
        const u16* nl = kl + (size_t)(nj * 64 + 16 * w + m16) * 64 + quad * 8;
#pragma unroll
        for (int ks = 0; ks < 2; ++ks) {
          ka[ks][0] = *(const s16x8*)(nr + ks * 32);
          ka[ks][1] = *(const s16x8*)(nl + ks * 32);
        }
      }
      __syncthreads();   // prior PV reads of P buffer complete
      // P^T -> LDS [q][k], packed b64 (regs are consecutive k)
#pragma unroll
      for (int nt = 0; nt < 4; ++nt) {
        float4 pv;
        pv.x = __expf(acc[nt][0] * 0.125f - Mq[nt]) * linq[nt];
        pv.y = __expf(acc[nt][1] * 0.125f - Mq[nt]) * linq[nt];
        pv.z = __expf(acc[nt][2] * 0.125f - Mq[nt]) * linq[nt];
        pv.w = __expf(acc[nt][3] * 0.125f - Mq[nt]) * linq[nt];
        u32x2 hi, lo; split4(pv, hi, lo);
        int off = (16 * nt + m16) * PTS + 16 * w + 4 * quad;
        *(u32x2*)(ph_ + off) = hi;
        *(u32x2*)(pl_ + off) = lo;
      }
      __syncthreads();
      // O^T strip += V^T . P^T
#pragma unroll
      for (int ks = 0; ks < 2; ++ks)
#pragma unroll
        for (int nt = 0; nt < 4; ++nt) {
          s16x8 pbh = *(const s16x8*)(ph_ + (16 * nt + m16) * PTS + ks * 32 + quad * 8);
          s16x8 pbl = *(const s16x8*)(pl_ + (16 * nt + m16) * PTS + ks * 32 + quad * 8);
          oacc[nt] = __builtin_amdgcn_mfma_f32_16x16x32_bf16(va[ks][0], pbh, oacc[nt], 0, 0, 0);
          oacc[nt] = __builtin_amdgcn_mfma_f32_16x16x32_bf16(va[ks][1], pbh, oacc[nt], 0, 0, 0);
          oacc[nt] = __builtin_amdgcn_mfma_f32_16x16x32_bf16(va[ks][0], pbl, oacc[nt], 0, 0, 0);
        }
      j = nj;
    }
  }

  // ---- store O: lane holds q = 16nt+m16, d = 16w+4quad (contiguous f32x4) ----
  float* ob = out + ((size_t)bh * L + (size_t)i * 64) * D;
#pragma unroll
  for (int nt = 0; nt < 4; ++nt)
    *(f32x4*)(ob + (16 * nt + m16) * 64 + 16 * w + 4 * quad) = oacc[nt];
}

// ---------------------------------------------------------------------------
extern "C" void kernel_launch(void* const* d_in, const int* in_sizes, int n_in,
                              void* d_out, int out_size, void* d_ws, size_t ws_size,
                              hipStream_t stream) {
  (void)in_sizes; (void)n_in; (void)out_size; (void)ws_size;
  const float* q   = (const float*)d_in[0];
  const float* k   = (const float*)d_in[1];
  const float* v   = (const float*)d_in[2];
  const float* cdf = (const float*)d_in[3];
  const float* sim = (const float*)d_in[4];
  const float* pvt = (const float*)d_in[5];
  float* out = (float*)d_out;

  uint8_t* w8 = (uint8_t*)d_ws;
  float* ksum  = (float*)w8;                          // 1024*64 f (256 KB)
  float* kmax2 = (float*)(w8 + 262144);               // 128 B
  u16* khi_g  = (u16*)(w8 + 262400);                  // 4 planes x 8 MB
  u16* klo_g  = khi_g + (size_t)B * H * L * D;
  u16* vthi_g = klo_g + (size_t)B * H * L * D;
  u16* vtlo_g = vthi_g + (size_t)B * H * L * D;

  hipMemsetAsync(kmax2, 0, B * H * sizeof(float), stream);
  k_prep<<<B * H * NB, 256, 0, stream>>>(k, v, ksum, khi_g, klo_g, vthi_g, vtlo_g, kmax2);
  k_attn<<<B * H * NB, 256, 0, stream>>>(q, ksum, khi_g, klo_g, vthi_g, vtlo_g,
                                         cdf, sim, pvt, kmax2, out);
}

// Round 6
// 325.287 us; speedup vs baseline: 1.0435x; 1.0435x over previous
//
#include <hip/hip_runtime.h>
#include <hip/hip_bf16.h>
#include <math.h>
#include <stdint.h>

#define B 2
#define H 16
#define L 2048
#define D 64
#define NB 32
#define PTS 72            // P tile row stride in u16 (144 B)

typedef unsigned short u16;
typedef unsigned int u32;
typedef __attribute__((ext_vector_type(2))) unsigned int u32x2;
typedef __attribute__((ext_vector_type(8))) short s16x8;
typedef __attribute__((ext_vector_type(4))) float f32x4;

union FragU { s16x8 v; u32 u[4]; };

__device__ __forceinline__ u32 pkbf(float a, float b) {
  __hip_bfloat162 h = __float22bfloat162_rn(make_float2(a, b));  // v_cvt_pk_bf16_f32
  union { __hip_bfloat162 h; u32 u; } cv; cv.h = h; return cv.u;
}
__device__ __forceinline__ float bf2f(u32 u16bits) {
  union { u32 u; float f; } c; c.u = u16bits << 16; return c.f;
}
// split float4 -> packed hi (u32x2) + lo (u32x2), RNE both levels
__device__ __forceinline__ void split4(float4 p, u32x2& hi, u32x2& lo) {
  u32 h01 = pkbf(p.x, p.y), h23 = pkbf(p.z, p.w);
  float rx = p.x - bf2f(h01 & 0xffffu);
  float ry = p.y - bf2f(h01 >> 16);
  float rz = p.z - bf2f(h23 & 0xffffu);
  float rw = p.w - bf2f(h23 >> 16);
  hi = (u32x2){h01, h23};
  lo = (u32x2){pkbf(rx, ry), pkbf(rz, rw)};
}

// ---------------------------------------------------------------------------
// k_prep: per (bh,j): K column-sums, K split hi/lo, V^T split hi/lo,
//         per-(bh,j) max ||k_row||^2 (no atomics)
// ---------------------------------------------------------------------------
__global__ __launch_bounds__(256) void k_prep(const float* __restrict__ k,
                                              const float* __restrict__ v,
                                              float* __restrict__ ksum,
                                              u16* __restrict__ khi_g,
                                              u16* __restrict__ klo_g,
                                              u16* __restrict__ vthi_g,
                                              u16* __restrict__ vtlo_g,
                                              float* __restrict__ kbmax) {
  int blk = blockIdx.x, bh = blk >> 5, j = blk & 31, t = threadIdx.x;
  __shared__ float vt[64 * 65];
  __shared__ float pk_[4][64];
  __shared__ unsigned bmaxS;
  if (t == 0) bmaxS = 0u;
  size_t base = (size_t)blk * 4096;
  {
    int d = t & 63, g = t >> 6;
    float sk = 0.f;
    for (int r = g * 16; r < g * 16 + 16; ++r) sk += k[base + r * 64 + d];
    pk_[g][d] = sk;
  }
  __syncthreads();
  if (t < 64) ksum[(size_t)blk * 64 + t] = pk_[0][t] + pk_[1][t] + pk_[2][t] + pk_[3][t];

  float rmax = 0.f;
  for (int it = 0; it < 4; ++it) {
    int idx = t + 256 * it, r = idx >> 4, c4 = (idx & 15) * 4;
    float4 f = *(const float4*)(k + base + r * 64 + c4);
    u32x2 hi, lo; split4(f, hi, lo);
    *(u32x2*)(khi_g + base + r * 64 + c4) = hi;
    *(u32x2*)(klo_g + base + r * 64 + c4) = lo;
    float ssq = f.x*f.x + f.y*f.y + f.z*f.z + f.w*f.w;
    ssq += __shfl_xor(ssq, 1); ssq += __shfl_xor(ssq, 2);
    ssq += __shfl_xor(ssq, 4); ssq += __shfl_xor(ssq, 8);
    if ((t & 15) == 0) rmax = fmaxf(rmax, ssq);
    float4 g2 = *(const float4*)(v + base + r * 64 + c4);
    vt[(c4 + 0) * 65 + r] = g2.x;
    vt[(c4 + 1) * 65 + r] = g2.y;
    vt[(c4 + 2) * 65 + r] = g2.z;
    vt[(c4 + 3) * 65 + r] = g2.w;
  }
  if ((t & 15) == 0) atomicMax(&bmaxS, __float_as_uint(rmax));
  __syncthreads();
  if (t == 0) kbmax[blk] = __uint_as_float(bmaxS);
  for (int it = 0; it < 2; ++it) {
    int idx = t + 256 * it, d = idx >> 3, s8 = (idx & 7) * 8;
    const float* vr = &vt[d * 65 + s8];
    float4 f0 = {vr[0], vr[1], vr[2], vr[3]};
    float4 f1 = {vr[4], vr[5], vr[6], vr[7]};
    u32x2 h0, l0, h1, l1;
    split4(f0, h0, l0); split4(f1, h1, l1);
    size_t o = (size_t)bh * 131072 + (size_t)d * 2048 + j * 64 + s8;
    *(u32x2*)(vthi_g + o) = h0; *(u32x2*)(vthi_g + o + 4) = h1;
    *(u32x2*)(vtlo_g + o) = l0; *(u32x2*)(vtlo_g + o + 4) = l1;
  }
}

// ---------------------------------------------------------------------------
// k_attn: fused mask + two-pass MFMA attention (S^T = K·Q^T, O^T = V^T·P^T)
// bh = blk>>5: consecutive WGs share one bh's planes (blocked XCD fill -> L2 hot)
// ---------------------------------------------------------------------------
__global__ __launch_bounds__(256, 4) void k_attn(
    const float* __restrict__ q,
    const float* __restrict__ ksum,
    const u16* __restrict__ khi_g, const u16* __restrict__ klo_g,
    const u16* __restrict__ vthi_g, const u16* __restrict__ vtlo_g,
    const float* __restrict__ cdfthreshd, const float* __restrict__ simthreshd1,
    const float* __restrict__ pvthreshd, const float* __restrict__ kbmax,
    float* __restrict__ out) {
  int blk = blockIdx.x, bh = blk >> 5, i = blk & 31, h = bh & (H - 1);
  int t = threadIdx.x, lane = t & 63, w = t >> 6;
  int m16 = lane & 15, quad = lane >> 4;

  __shared__ __align__(16) uint8_t smem[28692];
  float* qf32  = (float*)smem;                    // 64 x 68 f32, setup only (aliases pbuf)
  u32*   rbm   = (u32*)(smem + 18432);            // 64 x 33 uint keys (-(s-M))
  float* MS    = (float*)(smem + 26880);          // 64
  float* linvS = (float*)(smem + 27136);          // 64
  float* lpart = (float*)(smem + 27392);          // [4][64]
  float* qmS   = (float*)(smem + 28416);          // 64
  int*   pooledS = (int*)(smem + 28672);
  u32*   mwS     = (u32*)(smem + 28676);
  u32*   gmS     = (u32*)(smem + 28680);
  float* kmax2S  = (float*)(smem + 28684);
  u16* ph_ = (u16*)smem;                          // P hi plane (pass B)
  u16* pl_ = (u16*)(smem + 9216);                 // P lo plane

  const float* qg = q + ((size_t)bh * L + (size_t)i * 64) * D;
  const u16* kh = khi_g + (size_t)bh * (L * D);
  const u16* kl = klo_g + (size_t)bh * (L * D);
  const u16* vh = vthi_g + (size_t)bh * (L * D);
  const u16* vl = vtlo_g + (size_t)bh * (L * D);

  // ---- Q B-fragments straight from global (f32 -> split, registers) ----
  s16x8 qhf[4][2], qlf[4][2];
#pragma unroll
  for (int nt = 0; nt < 4; ++nt)
#pragma unroll
    for (int ks = 0; ks < 2; ++ks) {
      const float* p0 = qg + (16 * nt + m16) * 64 + ks * 32 + quad * 8;
      float4 a = *(const float4*)p0;
      float4 b2 = *(const float4*)(p0 + 4);
      u32x2 ha, la, hb, lb;
      split4(a, ha, la); split4(b2, hb, lb);
      FragU fh, fl;
      fh.u[0] = ha[0]; fh.u[1] = ha[1]; fh.u[2] = hb[0]; fh.u[3] = hb[1];
      fl.u[0] = la[0]; fl.u[1] = la[1]; fl.u[2] = lb[0]; fl.u[3] = lb[1];
      qhf[nt][ks] = fh.v; qlf[nt][ks] = fl.v;
    }
  // stage Q f32 for mask math
  for (int it = 0; it < 4; ++it) {
    int idx = t + 256 * it, r = idx >> 4, c4 = (idx & 15) * 4;
    *(float4*)&qf32[r * 68 + c4] = ((const float4*)qg)[idx];
  }
  for (int e = t; e < 64 * 33; e += 256) rbm[e] = 0x7F800000u;  // +inf keys
  __syncthreads();

  // ---- wave0: qm; wave3: kmax2 = max_j kbmax[bh][j] ----
  if (w == 0) {
    float s = 0.f;
    for (int r = 0; r < 64; ++r) s += qf32[r * 68 + lane];
    qmS[lane] = s * (1.f / 64.f);
  }
  if (w == 3) {
    float m = (lane < 32) ? kbmax[bh * 32 + lane] : 0.f;
    for (int off = 16; off; off >>= 1) m = fmaxf(m, __shfl_xor(m, off, 32));
    if (lane == 0) *kmax2S = m;
  }
  __syncthreads();

  // ---- wave0: CDF block-keep; wave1: pooled cosine + M rows ----
  bool keepj = false;
  if (w == 0 && lane < 32) {
    int j = lane;
    const float* ksp = ksum + (size_t)bh * NB * 64 + j * 64;
    float sv = 0.f;
    for (int d = 0; d < 64; ++d) sv += qmS[d] * ksp[d];
    sv *= (1.f / 64.f) * 0.125f;     // mean shift cancels in softmax
    float mx = sv;
    for (int off = 16; off; off >>= 1) mx = fmaxf(mx, __shfl_xor(mx, off, 32));
    float p = expf(sv - mx);
    float sum = p;
    for (int off = 16; off; off >>= 1) sum += __shfl_xor(sum, off, 32);
    p /= sum;
    float excl = 0.f;
    for (int u = 0; u < 32; ++u) {
      float pu = __shfl(p, u, 32);
      if ((pu > p) || (pu == p && u < j)) excl += pu;
    }
    keepj = excl < cdfthreshd[h];
  }
  if (w == 1) {
    int r = lane;
    float dot = 0.f, qn2 = 0.f, qmn2 = 0.f;
    for (int d = 0; d < 64; ++d) {
      float a = qf32[r * 68 + d], b2 = qmS[d];
      dot += a * b2; qn2 += a * a; qmn2 += b2 * b2;
    }
    float cs = dot / (sqrtf(qn2) * sqrtf(qmn2) + 1e-6f);
    float su = cs;
    for (int off = 32; off; off >>= 1) su += __shfl_xor(su, off);
    if (lane == 0) *pooledS = (su * (1.f / 64.f)) > simthreshd1[h];
    MS[r] = sqrtf(qn2 * (*kmax2S)) * 0.125f;   // M_r = ||q_r||*Kmax*scale >= |s|
  }
  __syncthreads();
  if (w == 0 && lane < 32) {
    bool bit = keepj || !(*pooledS) || (lane == 0);
    unsigned long long bal = __ballot(bit);
    if (lane == 0) *mwS = (u32)bal;
  }
  __syncthreads();
  u32 mw = *mwS;

  float Mq[4];
#pragma unroll
  for (int nt = 0; nt < 4; ++nt) Mq[nt] = MS[16 * nt + m16];

  // ---- Pass A: barrier-free; K A-frags from global; per-lane l; rbm atomics ----
  float lp[4] = {0.f, 0.f, 0.f, 0.f};
  {
    int j = (int)__builtin_ctz(mw);
    u32 rm_ = mw & (mw - 1);
    s16x8 ka[2][2], kan[2][2];
    const u16* kr0 = kh + (size_t)(j * 64 + 16 * w + m16) * 64 + quad * 8;
    const u16* kl0 = kl + (size_t)(j * 64 + 16 * w + m16) * 64 + quad * 8;
#pragma unroll
    for (int ks = 0; ks < 2; ++ks) {
      ka[ks][0] = *(const s16x8*)(kr0 + ks * 32);
      ka[ks][1] = *(const s16x8*)(kl0 + ks * 32);
    }
    for (;;) {
      int nj = -1;
      if (rm_) {
        nj = (int)__builtin_ctz(rm_); rm_ &= rm_ - 1;
        const u16* nr = kh + (size_t)(nj * 64 + 16 * w + m16) * 64 + quad * 8;
        const u16* nl = kl + (size_t)(nj * 64 + 16 * w + m16) * 64 + quad * 8;
#pragma unroll
        for (int ks = 0; ks < 2; ++ks) {
          kan[ks][0] = *(const s16x8*)(nr + ks * 32);
          kan[ks][1] = *(const s16x8*)(nl + ks * 32);
        }
      }
      f32x4 acc[4];
#pragma unroll
      for (int nt = 0; nt < 4; ++nt) acc[nt] = (f32x4){0.f, 0.f, 0.f, 0.f};
#pragma unroll
      for (int ks = 0; ks < 2; ++ks)
#pragma unroll
        for (int nt = 0; nt < 4; ++nt) {
          acc[nt] = __builtin_amdgcn_mfma_f32_16x16x32_bf16(ka[ks][0], qhf[nt][ks], acc[nt], 0, 0, 0);
          acc[nt] = __builtin_amdgcn_mfma_f32_16x16x32_bf16(ka[ks][1], qhf[nt][ks], acc[nt], 0, 0, 0);
          acc[nt] = __builtin_amdgcn_mfma_f32_16x16x32_bf16(ka[ks][0], qlf[nt][ks], acc[nt], 0, 0, 0);
        }
#pragma unroll
      for (int nt = 0; nt < 4; ++nt) {
        float vmax = -1e30f;
#pragma unroll
        for (int reg = 0; reg < 4; ++reg) {
          float s = acc[nt][reg] * 0.125f - Mq[nt];
          lp[nt] += __expf(s);
          vmax = fmaxf(vmax, s);
        }
        vmax = fmaxf(vmax, __shfl_xor(vmax, 16));
        vmax = fmaxf(vmax, __shfl_xor(vmax, 32));
        if (quad == 0)
          atomicMin(&rbm[(16 * nt + m16) * 33 + j], __float_as_uint(fmaxf(-vmax, 0.f)));
      }
      if (nj < 0) break;
#pragma unroll
      for (int ks = 0; ks < 2; ++ks) { ka[ks][0] = kan[ks][0]; ka[ks][1] = kan[ks][1]; }
      j = nj;
    }
  }
#pragma unroll
  for (int nt = 0; nt < 4; ++nt) {
    float s = lp[nt];
    s += __shfl_xor(s, 16); s += __shfl_xor(s, 32);
    if (quad == 0) lpart[w * 64 + 16 * nt + m16] = s;
  }
  __syncthreads();
  if (t < 64) linvS[t] = 1.f / (lpart[t] + lpart[64 + t] + lpart[128 + t] + lpart[192 + t]);
  __syncthreads();

  // ---- PV gate ----
  if (t < 32) {
    bool keep = (mw >> t) & 1u;
    if (keep && t != 0) {
      float thr = pvthreshd[h] * 1e-3f;
      float mp = 0.f;
      for (int r = 0; r < 64; ++r) {
        float key = __uint_as_float(rbm[r * 33 + t]);
        mp = fmaxf(mp, __expf(-key) * linvS[r]);
      }
      keep = mp >= thr;
    }
    unsigned long long bal = __ballot(keep);
    if (t == 0) *gmS = (u32)bal;
  }
  __syncthreads();
  u32 gm = *gmS;

  // ---- Pass B: S recompute -> P^T (single LDS buf) -> O^T += V^T . P^T ----
  float linq[4];
#pragma unroll
  for (int nt = 0; nt < 4; ++nt) linq[nt] = linvS[16 * nt + m16];
  f32x4 oacc[4];
#pragma unroll
  for (int nt = 0; nt < 4; ++nt) oacc[nt] = (f32x4){0.f, 0.f, 0.f, 0.f};

  {
    int j = -1;
    u32 g2 = gm;
    s16x8 ka[2][2];
    if (g2) {
      j = (int)__builtin_ctz(g2); g2 &= g2 - 1;
      const u16* kr0 = kh + (size_t)(j * 64 + 16 * w + m16) * 64 + quad * 8;
      const u16* kl0 = kl + (size_t)(j * 64 + 16 * w + m16) * 64 + quad * 8;
#pragma unroll
      for (int ks = 0; ks < 2; ++ks) {
        ka[ks][0] = *(const s16x8*)(kr0 + ks * 32);
        ka[ks][1] = *(const s16x8*)(kl0 + ks * 32);
      }
    }
    while (j >= 0) {
      // V^T A-frags for current j
      s16x8 va[2][2];
      const u16* vr0 = vh + (size_t)(16 * w + m16) * L + j * 64 + quad * 8;
      const u16* vl0 = vl + (size_t)(16 * w + m16) * L + j * 64 + quad * 8;
#pragma unroll
      for (int ks = 0; ks < 2; ++ks) {
        va[ks][0] = *(const s16x8*)(vr0 + ks * 32);
        va[ks][1] = *(const s16x8*)(vl0 + ks * 32);
      }
      f32x4 acc[4];
#pragma unroll
      for (int nt = 0; nt < 4; ++nt) acc[nt] = (f32x4){0.f, 0.f, 0.f, 0.f};
#pragma unroll
      for (int ks = 0; ks < 2; ++ks)
#pragma unroll
        for (int nt = 0; nt < 4; ++nt) {
          acc[nt] = __builtin_amdgcn_mfma_f32_16x16x32_bf16(ka[ks][0], qhf[nt][ks], acc[nt], 0, 0, 0);
          acc[nt] = __builtin_amdgcn_mfma_f32_16x16x32_bf16(ka[ks][1], qhf[nt][ks], acc[nt], 0, 0, 0);
          acc[nt] = __builtin_amdgcn_mfma_f32_16x16x32_bf16(ka[ks][0], qlf[nt][ks], acc[nt], 0, 0, 0);
        }
      // prefetch next K
      int nj = -1;
      if (g2) {
        nj = (int)__builtin_ctz(g2); g2 &= g2 - 1;
        const u16* nr = kh + (size_t)(nj * 64 + 16 * w + m16) * 64 + quad * 8;
        const u16* nl = kl + (size_t)(nj * 64 + 16 * w + m16) * 64 + quad * 8;
#pragma unroll
        for (int ks = 0; ks < 2; ++ks) {
          ka[ks][0] = *(const s16x8*)(nr + ks * 32);
          ka[ks][1] = *(const s16x8*)(nl + ks * 32);
        }
      }
      __syncthreads();   // prior PV reads of P buffer complete
      // P^T -> LDS [q][k], packed b64 (regs are consecutive k)
#pragma unroll
      for (int nt = 0; nt < 4; ++nt) {
        float4 pv;
        pv.x = __expf(acc[nt][0] * 0.125f - Mq[nt]) * linq[nt];
        pv.y = __expf(acc[nt][1] * 0.125f - Mq[nt]) * linq[nt];
        pv.z = __expf(acc[nt][2] * 0.125f - Mq[nt]) * linq[nt];
        pv.w = __expf(acc[nt][3] * 0.125f - Mq[nt]) * linq[nt];
        u32x2 hi, lo; split4(pv, hi, lo);
        int off = (16 * nt + m16) * PTS + 16 * w + 4 * quad;
        *(u32x2*)(ph_ + off) = hi;
        *(u32x2*)(pl_ + off) = lo;
      }
      __syncthreads();
      // O^T strip += V^T . P^T
#pragma unroll
      for (int ks = 0; ks < 2; ++ks)
#pragma unroll
        for (int nt = 0; nt < 4; ++nt) {
          s16x8 pbh = *(const s16x8*)(ph_ + (16 * nt + m16) * PTS + ks * 32 + quad * 8);
          s16x8 pbl = *(const s16x8*)(pl_ + (16 * nt + m16) * PTS + ks * 32 + quad * 8);
          oacc[nt] = __builtin_amdgcn_mfma_f32_16x16x32_bf16(va[ks][0], pbh, oacc[nt], 0, 0, 0);
          oacc[nt] = __builtin_amdgcn_mfma_f32_16x16x32_bf16(va[ks][1], pbh, oacc[nt], 0, 0, 0);
          oacc[nt] = __builtin_amdgcn_mfma_f32_16x16x32_bf16(va[ks][0], pbl, oacc[nt], 0, 0, 0);
        }
      j = nj;
    }
  }

  // ---- store O: lane holds q = 16nt+m16, d = 16w+4quad (contiguous f32x4) ----
  float* ob = out + ((size_t)bh * L + (size_t)i * 64) * D;
#pragma unroll
  for (int nt = 0; nt < 4; ++nt)
    *(f32x4*)(ob + (16 * nt + m16) * 64 + 16 * w + 4 * quad) = oacc[nt];
}

// ---------------------------------------------------------------------------
extern "C" void kernel_launch(void* const* d_in, const int* in_sizes, int n_in,
                              void* d_out, int out_size, void* d_ws, size_t ws_size,
                              hipStream_t stream) {
  (void)in_sizes; (void)n_in; (void)out_size; (void)ws_size;
  const float* q   = (const float*)d_in[0];
  const float* k   = (const float*)d_in[1];
  const float* v   = (const float*)d_in[2];
  const float* cdf = (const float*)d_in[3];
  const float* sim = (const float*)d_in[4];
  const float* pvt = (const float*)d_in[5];
  float* out = (float*)d_out;

  uint8_t* w8 = (uint8_t*)d_ws;
  float* ksum  = (float*)w8;                          // 1024*64 f (256 KB)
  float* kbmax = (float*)(w8 + 262144);               // 1024 f (4 KB)
  u16* khi_g  = (u16*)(w8 + 266240);                  // 4 planes x 8 MB
  u16* klo_g  = khi_g + (size_t)B * H * L * D;
  u16* vthi_g = klo_g + (size_t)B * H * L * D;
  u16* vtlo_g = vthi_g + (size_t)B * H * L * D;

  k_prep<<<B * H * NB, 256, 0, stream>>>(k, v, ksum, khi_g, klo_g, vthi_g, vtlo_g, kbmax);
  k_attn<<<B * H * NB, 256, 0, stream>>>(q, ksum, khi_g, klo_g, vthi_g, vtlo_g,
                                         cdf, sim, pvt, kbmax, out);
}

// Round 8
// 224.495 us; speedup vs baseline: 1.5120x; 1.4490x over previous
//
#include <hip/hip_runtime.h>
#include <hip/hip_bf16.h>
#include <math.h>
#include <stdint.h>

#define B 2
#define H 16
#define L 2048
#define D 64
#define NB 32
#define PTS 72            // P tile row stride in u16 (144 B)

typedef unsigned short u16;
typedef unsigned int u32;
typedef __attribute__((ext_vector_type(2))) unsigned int u32x2;
typedef __attribute__((ext_vector_type(8))) short s16x8;
typedef __attribute__((ext_vector_type(4))) float f32x4;

union FragU { s16x8 v; u32 u[4]; };

__device__ __forceinline__ u32 pkbf(float a, float b) {
  __hip_bfloat162 h = __float22bfloat162_rn(make_float2(a, b));  // v_cvt_pk_bf16_f32
  union { __hip_bfloat162 h; u32 u; } cv; cv.h = h; return cv.u;
}
__device__ __forceinline__ float bf2f(u32 u16bits) {
  union { u32 u; float f; } c; c.u = u16bits << 16; return c.f;
}
// split float4 -> packed hi (u32x2) + lo (u32x2), RNE both levels
__device__ __forceinline__ void split4(float4 p, u32x2& hi, u32x2& lo) {
  u32 h01 = pkbf(p.x, p.y), h23 = pkbf(p.z, p.w);
  float rx = p.x - bf2f(h01 & 0xffffu);
  float ry = p.y - bf2f(h01 >> 16);
  float rz = p.z - bf2f(h23 & 0xffffu);
  float rw = p.w - bf2f(h23 >> 16);
  hi = (u32x2){h01, h23};
  lo = (u32x2){pkbf(rx, ry), pkbf(rz, rw)};
}

// ---------------------------------------------------------------------------
// k_prep: per (bh,j): K column-sums, K split hi/lo, V^T split hi/lo,
//         per-(bh,j) max ||k_row||^2 (no global atomics)
// ---------------------------------------------------------------------------
__global__ __launch_bounds__(256) void k_prep(const float* __restrict__ k,
                                              const float* __restrict__ v,
                                              float* __restrict__ ksum,
                                              u16* __restrict__ khi_g,
                                              u16* __restrict__ klo_g,
                                              u16* __restrict__ vthi_g,
                                              u16* __restrict__ vtlo_g,
                                              float* __restrict__ kbmax) {
  int blk = blockIdx.x, bh = blk >> 5, j = blk & 31, t = threadIdx.x;
  __shared__ float vt[64 * 65];
  __shared__ float pk_[4][64];
  __shared__ unsigned bmaxS;
  if (t == 0) bmaxS = 0u;
  size_t base = (size_t)blk * 4096;
  {
    int d = t & 63, g = t >> 6;
    float sk = 0.f;
    for (int r = g * 16; r < g * 16 + 16; ++r) sk += k[base + r * 64 + d];
    pk_[g][d] = sk;
  }
  __syncthreads();
  if (t < 64) ksum[(size_t)blk * 64 + t] = pk_[0][t] + pk_[1][t] + pk_[2][t] + pk_[3][t];

  float rmax = 0.f;
  for (int it = 0; it < 4; ++it) {
    int idx = t + 256 * it, r = idx >> 4, c4 = (idx & 15) * 4;
    float4 f = *(const float4*)(k + base + r * 64 + c4);
    u32x2 hi, lo; split4(f, hi, lo);
    *(u32x2*)(khi_g + base + r * 64 + c4) = hi;
    *(u32x2*)(klo_g + base + r * 64 + c4) = lo;
    float ssq = f.x*f.x + f.y*f.y + f.z*f.z + f.w*f.w;
    ssq += __shfl_xor(ssq, 1); ssq += __shfl_xor(ssq, 2);
    ssq += __shfl_xor(ssq, 4); ssq += __shfl_xor(ssq, 8);
    if ((t & 15) == 0) rmax = fmaxf(rmax, ssq);
    float4 g2 = *(const float4*)(v + base + r * 64 + c4);
    vt[(c4 + 0) * 65 + r] = g2.x;
    vt[(c4 + 1) * 65 + r] = g2.y;
    vt[(c4 + 2) * 65 + r] = g2.z;
    vt[(c4 + 3) * 65 + r] = g2.w;
  }
  if ((t & 15) == 0) atomicMax(&bmaxS, __float_as_uint(rmax));
  __syncthreads();
  if (t == 0) kbmax[blk] = __uint_as_float(bmaxS);
  for (int it = 0; it < 2; ++it) {
    int idx = t + 256 * it, d = idx >> 3, s8 = (idx & 7) * 8;
    const float* vr = &vt[d * 65 + s8];
    float4 f0 = {vr[0], vr[1], vr[2], vr[3]};
    float4 f1 = {vr[4], vr[5], vr[6], vr[7]};
    u32x2 h0, l0, h1, l1;
    split4(f0, h0, l0); split4(f1, h1, l1);
    size_t o = (size_t)bh * 131072 + (size_t)d * 2048 + j * 64 + s8;
    *(u32x2*)(vthi_g + o) = h0; *(u32x2*)(vthi_g + o + 4) = h1;
    *(u32x2*)(vtlo_g + o) = l0; *(u32x2*)(vtlo_g + o + 4) = l1;
  }
}

// ---------------------------------------------------------------------------
// k_attn: 2 q-blocks per WG, union-mask K sweep (one K load -> both q-blocks)
// 512 WGs at exactly 2 WGs/CU (LDS-padded). bh = blk>>4 for L2 locality.
// LDS map (bytes):
//   0      P hi qb0   9216     P lo qb0   18432  P hi qb1   27648  P lo qb1
//   36864  rbm qb0 (64*33 u32) 45312 rbm qb1    53760 MS[128]  54272 linv[128]
//   54784  lpart[4][128]       56832 qm[2][64]  57344 flags[7]
// ---------------------------------------------------------------------------
#define RBM_OFF 36864
#define MS_OFF 53760
#define LINV_OFF 54272
#define LPART_OFF 54784
#define QM_OFF 56832
#define FLG_OFF 57344

__global__ __launch_bounds__(256, 2) void k_attn(
    const float* __restrict__ q,
    const float* __restrict__ ksum,
    const u16* __restrict__ khi_g, const u16* __restrict__ klo_g,
    const u16* __restrict__ vthi_g, const u16* __restrict__ vtlo_g,
    const float* __restrict__ cdfthreshd, const float* __restrict__ simthreshd1,
    const float* __restrict__ pvthreshd, const float* __restrict__ kbmax,
    float* __restrict__ out) {
  int blk = blockIdx.x, bh = blk >> 4, ip = blk & 15, h = bh & (H - 1);
  int t = threadIdx.x, lane = t & 63, w = t >> 6;
  int m16 = lane & 15, quad = lane >> 4;

  __shared__ __align__(16) uint8_t smem[57376];
  u16*   pbase = (u16*)smem;                     // ph(qb) = pbase + qb*18432/2... see macros
  u32*   rbm0  = (u32*)(smem + RBM_OFF);         // rbm(qb) = rbm0 + qb*64*33
  float* MS    = (float*)(smem + MS_OFF);
  float* linvS = (float*)(smem + LINV_OFF);
  float* lpart = (float*)(smem + LPART_OFF);
  float* qmS   = (float*)(smem + QM_OFF);
  int*   flg   = (int*)(smem + FLG_OFF);
#define PHQ(qb) (pbase + (qb) * 9216)            // u16 units: qb0 hi @0, qb1 hi @18432B
#define PLQ(qb) (pbase + 4608 + (qb) * 9216)     // qb0 lo @9216B, qb1 lo @27648B

  const float* qg0 = q + ((size_t)bh * L + (size_t)(2 * ip) * 64) * D;
  const float* qg1 = qg0 + 64 * D;
  const u16* kh = khi_g + (size_t)bh * (L * D);
  const u16* kl = klo_g + (size_t)bh * (L * D);
  const u16* vh = vthi_g + (size_t)bh * (L * D);
  const u16* vl = vtlo_g + (size_t)bh * (L * D);

  // ---- Q B-fragments from global (f32 -> split, registers) ----
  s16x8 qhf[2][4][2], qlf[2][4][2];
#pragma unroll
  for (int qb = 0; qb < 2; ++qb) {
    const float* qgq = qb ? qg1 : qg0;
#pragma unroll
    for (int nt = 0; nt < 4; ++nt)
#pragma unroll
      for (int ks = 0; ks < 2; ++ks) {
        const float* p0 = qgq + (16 * nt + m16) * 64 + ks * 32 + quad * 8;
        float4 a = *(const float4*)p0;
        float4 b2 = *(const float4*)(p0 + 4);
        u32x2 ha, la, hb, lb;
        split4(a, ha, la); split4(b2, hb, lb);
        FragU fh, fl;
        fh.u[0] = ha[0]; fh.u[1] = ha[1]; fh.u[2] = hb[0]; fh.u[3] = hb[1];
        fl.u[0] = la[0]; fl.u[1] = la[1]; fl.u[2] = lb[0]; fl.u[3] = lb[1];
        qhf[qb][nt][ks] = fh.v; qlf[qb][nt][ks] = fl.v;
      }
  }
  for (int e = t; e < 2 * 64 * 33; e += 256)
    rbm0[e] = 0x7F800000u;   // +inf keys (rbm0, rbm1 contiguous)

  // ---- phase 1: qm per qb (w0,w2), kmax2 (w1) ----
  if (w == 0 || w == 2) {
    int qb = w >> 1;
    const float* qgq = qb ? qg1 : qg0;
    float s = 0.f;
    for (int r = 0; r < 64; ++r) s += qgq[r * 64 + lane];
    qmS[qb * 64 + lane] = s * (1.f / 64.f);
  }
  if (w == 1) {
    float m = (lane < 32) ? kbmax[bh * 32 + lane] : 0.f;
    for (int off = 16; off; off >>= 1) m = fmaxf(m, __shfl_xor(m, off, 32));
    if (lane == 0) ((float*)flg)[6] = m;
  }
  __syncthreads();

  // ---- phase 2: CDF keep (w0:qb0, w2:qb1); pooled cos + M (w1:qb0, w3:qb1) ----
  bool keepj = false;
  if ((w == 0 || w == 2) && lane < 32) {
    int qb = w >> 1, j = lane;
    const float* qmv = qmS + qb * 64;
    const float* ksp = ksum + (size_t)bh * NB * 64 + j * 64;
    float sv = 0.f;
    for (int d = 0; d < 64; ++d) sv += qmv[d] * ksp[d];
    sv *= (1.f / 64.f) * 0.125f;
    float mx = sv;
    for (int off = 16; off; off >>= 1) mx = fmaxf(mx, __shfl_xor(mx, off, 32));
    float p = expf(sv - mx);
    float sum = p;
    for (int off = 16; off; off >>= 1) sum += __shfl_xor(sum, off, 32);
    p /= sum;
    float excl = 0.f;
    for (int u = 0; u < 32; ++u) {
      float pu = __shfl(p, u, 32);
      if ((pu > p) || (pu == p && u < j)) excl += pu;
    }
    keepj = excl < cdfthreshd[h];
  }
  if (w == 1 || w == 3) {
    int qb = w >> 1, r = lane;
    const float* qgq = qb ? qg1 : qg0;
    const float* qmv = qmS + qb * 64;
    float kmax2 = ((float*)flg)[6];
    float dot = 0.f, qn2 = 0.f, qmn2 = 0.f;
    for (int d = 0; d < 64; ++d) {
      float a = qgq[r * 64 + d], b2 = qmv[d];
      dot += a * b2; qn2 += a * a; qmn2 += b2 * b2;
    }
    float cs = dot / (sqrtf(qn2) * sqrtf(qmn2) + 1e-6f);
    float su = cs;
    for (int off = 32; off; off >>= 1) su += __shfl_xor(su, off);
    if (lane == 0) flg[qb] = (su * (1.f / 64.f)) > simthreshd1[h];
    MS[qb * 64 + r] = sqrtf(qn2 * kmax2) * 0.125f;  // M_r >= |s| (Cauchy-Schwarz)
  }
  __syncthreads();
  if ((w == 0 || w == 2) && lane < 32) {
    int qb = w >> 1;
    bool bit = keepj || !flg[qb] || (lane == 0);
    unsigned long long bal = __ballot(bit);
    if (lane == 0) flg[2 + qb] = (int)(u32)bal;
  }
  __syncthreads();
  u32 mw0 = (u32)flg[2], mw1 = (u32)flg[3];

  float Mq[2][4];
#pragma unroll
  for (int qb = 0; qb < 2; ++qb)
#pragma unroll
    for (int nt = 0; nt < 4; ++nt) Mq[qb][nt] = MS[qb * 64 + 16 * nt + m16];

  // ---- Pass A: union sweep, one K load serves both q-blocks ----
  float lp[2][4] = {{0.f,0.f,0.f,0.f},{0.f,0.f,0.f,0.f}};
  {
    u32 mwU = mw0 | mw1;
    int j = (int)__builtin_ctz(mwU);
    u32 rm_ = mwU & (mwU - 1);
    s16x8 ka[2][2], kan[2][2];
    {
      const u16* kr0 = kh + (size_t)(j * 64 + 16 * w + m16) * 64 + quad * 8;
      const u16* kl0 = kl + (size_t)(j * 64 + 16 * w + m16) * 64 + quad * 8;
#pragma unroll
      for (int ks = 0; ks < 2; ++ks) {
        ka[ks][0] = *(const s16x8*)(kr0 + ks * 32);
        ka[ks][1] = *(const s16x8*)(kl0 + ks * 32);
      }
    }
    for (;;) {
      int nj = -1;
      if (rm_) {
        nj = (int)__builtin_ctz(rm_); rm_ &= rm_ - 1;
        const u16* nr = kh + (size_t)(nj * 64 + 16 * w + m16) * 64 + quad * 8;
        const u16* nl = kl + (size_t)(nj * 64 + 16 * w + m16) * 64 + quad * 8;
#pragma unroll
        for (int ks = 0; ks < 2; ++ks) {
          kan[ks][0] = *(const s16x8*)(nr + ks * 32);
          kan[ks][1] = *(const s16x8*)(nl + ks * 32);
        }
      }
#pragma unroll
      for (int qb = 0; qb < 2; ++qb) {
        u32 mm = qb ? mw1 : mw0;
        if (!((mm >> j) & 1u)) continue;
        f32x4 acc[4];
#pragma unroll
        for (int nt = 0; nt < 4; ++nt) acc[nt] = (f32x4){0.f, 0.f, 0.f, 0.f};
#pragma unroll
        for (int ks = 0; ks < 2; ++ks)
#pragma unroll
          for (int nt = 0; nt < 4; ++nt) {
            acc[nt] = __builtin_amdgcn_mfma_f32_16x16x32_bf16(ka[ks][0], qhf[qb][nt][ks], acc[nt], 0, 0, 0);
            acc[nt] = __builtin_amdgcn_mfma_f32_16x16x32_bf16(ka[ks][1], qhf[qb][nt][ks], acc[nt], 0, 0, 0);
            acc[nt] = __builtin_amdgcn_mfma_f32_16x16x32_bf16(ka[ks][0], qlf[qb][nt][ks], acc[nt], 0, 0, 0);
          }
#pragma unroll
        for (int nt = 0; nt < 4; ++nt) {
          float vmax = -1e30f;
#pragma unroll
          for (int reg = 0; reg < 4; ++reg) {
            float s = acc[nt][reg] * 0.125f - Mq[qb][nt];
            lp[qb][nt] += __expf(s);
            vmax = fmaxf(vmax, s);
          }
          vmax = fmaxf(vmax, __shfl_xor(vmax, 16));
          vmax = fmaxf(vmax, __shfl_xor(vmax, 32));
          if (quad == 0)
            atomicMin(rbm0 + qb * (64 * 33) + (16 * nt + m16) * 33 + j,
                      __float_as_uint(fmaxf(-vmax, 0.f)));
        }
      }
      if (nj < 0) break;
#pragma unroll
      for (int ks = 0; ks < 2; ++ks) { ka[ks][0] = kan[ks][0]; ka[ks][1] = kan[ks][1]; }
      j = nj;
    }
  }
#pragma unroll
  for (int qb = 0; qb < 2; ++qb)
#pragma unroll
    for (int nt = 0; nt < 4; ++nt) {
      float s = lp[qb][nt];
      s += __shfl_xor(s, 16); s += __shfl_xor(s, 32);
      if (quad == 0) lpart[w * 128 + qb * 64 + 16 * nt + m16] = s;
    }
  __syncthreads();
  if (t < 128) linvS[t] = 1.f / (lpart[t] + lpart[128 + t] + lpart[256 + t] + lpart[384 + t]);
  __syncthreads();

  // ---- PV gate: wave0 -> qb0, wave1 -> qb1 ----
  if (w < 2 && lane < 32) {
    u32 mm = w ? mw1 : mw0;
    bool keep = (mm >> lane) & 1u;
    if (keep && lane != 0) {
      float thr = pvthreshd[h] * 1e-3f;
      const float* lin = linvS + w * 64;
      const u32* rb = rbm0 + w * (64 * 33);
      float mp = 0.f;
      for (int r = 0; r < 64; ++r) {
        float key = __uint_as_float(rb[r * 33 + lane]);
        mp = fmaxf(mp, __expf(-key) * lin[r]);
      }
      keep = mp >= thr;
    }
    unsigned long long bal = __ballot(keep);
    if (lane == 0) flg[4 + w] = (int)(u32)bal;
  }
  __syncthreads();
  u32 gm0 = (u32)flg[4], gm1 = (u32)flg[5];

  // ---- Pass B ----
  float linq[2][4];
#pragma unroll
  for (int qb = 0; qb < 2; ++qb)
#pragma unroll
    for (int nt = 0; nt < 4; ++nt) linq[qb][nt] = linvS[qb * 64 + 16 * nt + m16];
  f32x4 oacc[2][4];
#pragma unroll
  for (int qb = 0; qb < 2; ++qb)
#pragma unroll
    for (int nt = 0; nt < 4; ++nt) oacc[qb][nt] = (f32x4){0.f, 0.f, 0.f, 0.f};

  {
    u32 gmU = gm0 | gm1;
    int j = -1;
    u32 g2 = gmU;
    s16x8 ka[2][2];
    if (g2) {
      j = (int)__builtin_ctz(g2); g2 &= g2 - 1;
      const u16* kr0 = kh + (size_t)(j * 64 + 16 * w + m16) * 64 + quad * 8;
      const u16* kl0 = kl + (size_t)(j * 64 + 16 * w + m16) * 64 + quad * 8;
#pragma unroll
      for (int ks = 0; ks < 2; ++ks) {
        ka[ks][0] = *(const s16x8*)(kr0 + ks * 32);
        ka[ks][1] = *(const s16x8*)(kl0 + ks * 32);
      }
    }
    while (j >= 0) {
      int in0 = (gm0 >> j) & 1, in1 = (gm1 >> j) & 1;
      // V^T A-frags for current j (consumed late)
      s16x8 va[2][2];
      {
        const u16* vr0 = vh + (size_t)(16 * w + m16) * L + j * 64 + quad * 8;
        const u16* vl0 = vl + (size_t)(16 * w + m16) * L + j * 64 + quad * 8;
#pragma unroll
        for (int ks = 0; ks < 2; ++ks) {
          va[ks][0] = *(const s16x8*)(vr0 + ks * 32);
          va[ks][1] = *(const s16x8*)(vl0 + ks * 32);
        }
      }
      // S for qb0
      f32x4 acc[4];
      if (in0) {
#pragma unroll
        for (int nt = 0; nt < 4; ++nt) acc[nt] = (f32x4){0.f, 0.f, 0.f, 0.f};
#pragma unroll
        for (int ks = 0; ks < 2; ++ks)
#pragma unroll
          for (int nt = 0; nt < 4; ++nt) {
            acc[nt] = __builtin_amdgcn_mfma_f32_16x16x32_bf16(ka[ks][0], qhf[0][nt][ks], acc[nt], 0, 0, 0);
            acc[nt] = __builtin_amdgcn_mfma_f32_16x16x32_bf16(ka[ks][1], qhf[0][nt][ks], acc[nt], 0, 0, 0);
            acc[nt] = __builtin_amdgcn_mfma_f32_16x16x32_bf16(ka[ks][0], qlf[0][nt][ks], acc[nt], 0, 0, 0);
          }
      }
      __syncthreads();   // prior PV reads of P buffers complete
      if (in0) {
#pragma unroll
        for (int nt = 0; nt < 4; ++nt) {
          float4 pv;
          pv.x = __expf(acc[nt][0] * 0.125f - Mq[0][nt]) * linq[0][nt];
          pv.y = __expf(acc[nt][1] * 0.125f - Mq[0][nt]) * linq[0][nt];
          pv.z = __expf(acc[nt][2] * 0.125f - Mq[0][nt]) * linq[0][nt];
          pv.w = __expf(acc[nt][3] * 0.125f - Mq[0][nt]) * linq[0][nt];
          u32x2 hi, lo; split4(pv, hi, lo);
          int off = (16 * nt + m16) * PTS + 16 * w + 4 * quad;
          *(u32x2*)(PHQ(0) + off) = hi;
          *(u32x2*)(PLQ(0) + off) = lo;
        }
      }
      // S for qb1 (fills the barrier window), then P1 write
      if (in1) {
#pragma unroll
        for (int nt = 0; nt < 4; ++nt) acc[nt] = (f32x4){0.f, 0.f, 0.f, 0.f};
#pragma unroll
        for (int ks = 0; ks < 2; ++ks)
#pragma unroll
          for (int nt = 0; nt < 4; ++nt) {
            acc[nt] = __builtin_amdgcn_mfma_f32_16x16x32_bf16(ka[ks][0], qhf[1][nt][ks], acc[nt], 0, 0, 0);
            acc[nt] = __builtin_amdgcn_mfma_f32_16x16x32_bf16(ka[ks][1], qhf[1][nt][ks], acc[nt], 0, 0, 0);
            acc[nt] = __builtin_amdgcn_mfma_f32_16x16x32_bf16(ka[ks][0], qlf[1][nt][ks], acc[nt], 0, 0, 0);
          }
#pragma unroll
        for (int nt = 0; nt < 4; ++nt) {
          float4 pv;
          pv.x = __expf(acc[nt][0] * 0.125f - Mq[1][nt]) * linq[1][nt];
          pv.y = __expf(acc[nt][1] * 0.125f - Mq[1][nt]) * linq[1][nt];
          pv.z = __expf(acc[nt][2] * 0.125f - Mq[1][nt]) * linq[1][nt];
          pv.w = __expf(acc[nt][3] * 0.125f - Mq[1][nt]) * linq[1][nt];
          u32x2 hi, lo; split4(pv, hi, lo);
          int off = (16 * nt + m16) * PTS + 16 * w + 4 * quad;
          *(u32x2*)(PHQ(1) + off) = hi;
          *(u32x2*)(PLQ(1) + off) = lo;
        }
      }
      // prefetch next K (ka fully consumed)
      int nj = -1;
      if (g2) {
        nj = (int)__builtin_ctz(g2); g2 &= g2 - 1;
        const u16* nr = kh + (size_t)(nj * 64 + 16 * w + m16) * 64 + quad * 8;
        const u16* nl = kl + (size_t)(nj * 64 + 16 * w + m16) * 64 + quad * 8;
#pragma unroll
        for (int ks = 0; ks < 2; ++ks) {
          ka[ks][0] = *(const s16x8*)(nr + ks * 32);
          ka[ks][1] = *(const s16x8*)(nl + ks * 32);
        }
      }
      __syncthreads();
      // PV for both q-blocks (va shared)
#pragma unroll
      for (int qb = 0; qb < 2; ++qb) {
        if (!(qb ? in1 : in0)) continue;
        const u16* ph_ = PHQ(qb);
        const u16* pl_ = PLQ(qb);
#pragma unroll
        for (int ks = 0; ks < 2; ++ks)
#pragma unroll
          for (int nt = 0; nt < 4; ++nt) {
            s16x8 pbh = *(const s16x8*)(ph_ + (16 * nt + m16) * PTS + ks * 32 + quad * 8);
            s16x8 pbl = *(const s16x8*)(pl_ + (16 * nt + m16) * PTS + ks * 32 + quad * 8);
            oacc[qb][nt] = __builtin_amdgcn_mfma_f32_16x16x32_bf16(va[ks][0], pbh, oacc[qb][nt], 0, 0, 0);
            oacc[qb][nt] = __builtin_amdgcn_mfma_f32_16x16x32_bf16(va[ks][1], pbh, oacc[qb][nt], 0, 0, 0);
            oacc[qb][nt] = __builtin_amdgcn_mfma_f32_16x16x32_bf16(va[ks][0], pbl, oacc[qb][nt], 0, 0, 0);
          }
      }
      j = nj;
    }
  }

  // ---- store O: lane holds q-row = 16nt+m16, d = 16w+4quad (f32x4) ----
#pragma unroll
  for (int qb = 0; qb < 2; ++qb) {
    float* ob = out + ((size_t)bh * L + (size_t)(2 * ip + qb) * 64) * D;
#pragma unroll
    for (int nt = 0; nt < 4; ++nt)
      *(f32x4*)(ob + (16 * nt + m16) * 64 + 16 * w + 4 * quad) = oacc[qb][nt];
  }
}

// ---------------------------------------------------------------------------
extern "C" void kernel_launch(void* const* d_in, const int* in_sizes, int n_in,
                              void* d_out, int out_size, void* d_ws, size_t ws_size,
                              hipStream_t stream) {
  (void)in_sizes; (void)n_in; (void)out_size; (void)ws_size;
  const float* q   = (const float*)d_in[0];
  const float* k   = (const float*)d_in[1];
  const float* v   = (const float*)d_in[2];
  const float* cdf = (const float*)d_in[3];
  const float* sim = (const float*)d_in[4];
  const float* pvt = (const float*)d_in[5];
  float* out = (float*)d_out;

  uint8_t* w8 = (uint8_t*)d_ws;
  float* ksum  = (float*)w8;                          // 1024*64 f (256 KB)
  float* kbmax = (float*)(w8 + 262144);               // 1024 f (4 KB)
  u16* khi_g  = (u16*)(w8 + 266240);                  // 4 planes x 8 MB
  u16* klo_g  = khi_g + (size_t)B * H * L * D;
  u16* vthi_g = klo_g + (size_t)B * H * L * D;
  u16* vtlo_g = vthi_g + (size_t)B * H * L * D;

  k_prep<<<B * H * NB, 256, 0, stream>>>(k, v, ksum, khi_g, klo_g, vthi_g, vtlo_g, kbmax);
  k_attn<<<B * H * NB / 2, 256, 0, stream>>>(q, ksum, khi_g, klo_g, vthi_g, vtlo_g,
                                             cdf, sim, pvt, kbmax, out);
}